// Round 6
// baseline (115.850 us; speedup 1.0000x reference)
//
#include <hip/hip_runtime.h>
#include <hip/hip_bf16.h>
#include <math.h>

#define D_DIM 128
#define SIM_THR 0.2f
#define DEG_THR 3.0f
#define PT_THR 0.1
#define EPS_CS 1e-8
#define MARGIN 4e-3f
#define PK 4294967296.0   // 2^32: deg-count scale inside packed f64 atomic
#define CHUNK 2048        // edges scanned per block in partitioned edge_sim
#define NXCD 8

typedef unsigned short u16;

// ---------------- primary ws layout (bytes) ----------------
// 0        cd      double[N]   800000   (zeroed by node_pre)
// 800000   na      double[N]   800000
// 1600000  nx      f32[N]      400000   (|x| per node)
// 2000000  r_s     f32[N]      400000
// 2400000  r_d     f32[N]      400000
// 2800000  r_o     f32[N]      400000
// 3200000  e_arr   f32[E]      2560000
// 5760000  pack    f32[8N]     3200000  {r_s,r_d,r_o,|x|, as,ad,ao,inv_na}
// 8960000  flags   int[4]
// 8960016  G       f32[9]
#define WS_NEED 8960064

__device__ __forceinline__ float bf2f(u16 u) {
    return __uint_as_float(((unsigned)u) << 16);
}

// ---- K1: per node: xnorm bf16, |x|, r_k = dot(x,p_k); zero cd; block 0
//      wave 0 additionally computes prompt flags + 3x3 Gram ----
__global__ void node_pre_kernel(const float* __restrict__ x,
                                const float* __restrict__ ps,
                                const float* __restrict__ pd,
                                const float* __restrict__ po,
                                u16* __restrict__ xnorm,
                                float* __restrict__ nx,
                                float* __restrict__ rs,
                                float* __restrict__ rd,
                                float* __restrict__ ro,
                                double* __restrict__ cd,
                                int* __restrict__ flags,
                                float* __restrict__ G, int N) {
    int g = threadIdx.x >> 5;
    int lane = threadIdx.x & 31;
    int n = blockIdx.x * 8 + g;
    if (n < N) {
        int off = lane * 4;
        const float4 v = *(const float4*)(x + (size_t)n * D_DIM + off);
        const float4 s = *(const float4*)(ps + off);
        const float4 d = *(const float4*)(pd + off);
        const float4 o = *(const float4*)(po + off);
        float sq = v.x * v.x + v.y * v.y + v.z * v.z + v.w * v.w;
        float drs = v.x * s.x + v.y * s.y + v.z * s.z + v.w * s.w;
        float drd = v.x * d.x + v.y * d.y + v.z * d.z + v.w * d.w;
        float dro = v.x * o.x + v.y * o.y + v.z * o.z + v.w * o.w;
        for (int m = 16; m; m >>= 1) {
            sq += __shfl_xor(sq, m, 32);
            drs += __shfl_xor(drs, m, 32);
            drd += __shfl_xor(drd, m, 32);
            dro += __shfl_xor(dro, m, 32);
        }
        float nrm = sqrtf(sq);
        float inv = 1.0f / nrm;
        __hip_bfloat16 ob[4];
        ob[0] = __float2bfloat16(v.x * inv);
        ob[1] = __float2bfloat16(v.y * inv);
        ob[2] = __float2bfloat16(v.z * inv);
        ob[3] = __float2bfloat16(v.w * inv);
        *(ushort4*)(xnorm + (size_t)n * D_DIM + off) =
            make_ushort4(*(u16*)&ob[0], *(u16*)&ob[1], *(u16*)&ob[2], *(u16*)&ob[3]);
        if (lane == 0) {
            nx[n] = nrm;
            rs[n] = drs;
            rd[n] = drd;
            ro[n] = dro;
            cd[n] = 0.0;
        }
    }
    // prompt flags + Gram: one wave of block 0
    if (blockIdx.x == 0 && threadIdx.x < 64) {
        int t = threadIdx.x;
        float s0 = ps[t], s1 = ps[t + 64];
        float d0 = pd[t], d1 = pd[t + 64];
        float o0 = po[t], o1 = po[t + 64];
        float ss = s0 * s0 + s1 * s1;
        float sd = s0 * d0 + s1 * d1;
        float so = s0 * o0 + s1 * o1;
        float dd = d0 * d0 + d1 * d1;
        float dO = d0 * o0 + d1 * o1;
        float oo = o0 * o0 + o1 * o1;
        for (int m = 32; m; m >>= 1) {
            ss += __shfl_xor(ss, m);
            sd += __shfl_xor(sd, m);
            so += __shfl_xor(so, m);
            dd += __shfl_xor(dd, m);
            dO += __shfl_xor(dO, m);
            oo += __shfl_xor(oo, m);
        }
        unsigned long long zs = __ballot(s0 == 0.0f || s1 == 0.0f);
        unsigned long long zd = __ballot(d0 == 0.0f || d1 == 0.0f);
        unsigned long long zo = __ballot(o0 == 0.0f || o1 == 0.0f);
        if (t == 0) {
            flags[0] = (zs == 0ull);
            flags[1] = (zd == 0ull);
            flags[2] = (zo == 0ull);
            G[0] = ss; G[1] = sd; G[2] = so;
            G[3] = sd; G[4] = dd; G[5] = dO;
            G[6] = so; G[7] = dO; G[8] = oo;
        }
    }
}

// ---- K2: XCD-partitioned edge sim. blockIdx&7 -> XCD; each block scans one
//      CHUNK of edges, LDS-compacts those whose col is in its XCD's node
//      range (3.2MB of xnorm rows -> L2-resident), then gathers 4/group. ----
__global__ void edge_sim_part(const u16* __restrict__ xnorm,
                              const int* __restrict__ ei,
                              double* __restrict__ cd,
                              float* __restrict__ e_arr,
                              int E, int N) {
    __shared__ int s_list[CHUNK];
    __shared__ int s_cnt;
    int tid = threadIdx.x;
    if (tid == 0) s_cnt = 0;
    __syncthreads();

    int xcd = blockIdx.x & (NXCD - 1);
    int base = (blockIdx.x >> 3) * CHUNK;
    int range = (N + NXCD - 1) / NXCD;
    int lo = xcd * range;
    int hi = min(N, lo + range);

    for (int i = tid; i < CHUNK; i += 256) {
        int e = base + i;
        if (e < E) {
            int col = ei[E + e];
            if (col >= lo && col < hi) {
                int idx = atomicAdd(&s_cnt, 1);
                s_list[idx] = e;
            }
        }
    }
    __syncthreads();

    int cnt = s_cnt;
    int lane = tid & 31;
    int grp = tid >> 5;
    for (int b = grp * 4; b < cnt; b += 32) {
        int r[4], c4[4];
        #pragma unroll
        for (int k = 0; k < 4; ++k) {
            int p = b + k;
            int src = s_list[(p < cnt) ? p : b];
            r[k] = ei[src];
            c4[k] = ei[E + src];
        }
        ushort4 a[4], bb[4];
        #pragma unroll
        for (int k = 0; k < 4; ++k) {
            a[k]  = *(const ushort4*)(xnorm + (size_t)r[k] * D_DIM + lane * 4);
            bb[k] = *(const ushort4*)(xnorm + (size_t)c4[k] * D_DIM + lane * 4);
        }
        float d[4];
        #pragma unroll
        for (int k = 0; k < 4; ++k) {
            d[k] = bf2f(a[k].x) * bf2f(bb[k].x) + bf2f(a[k].y) * bf2f(bb[k].y) +
                   bf2f(a[k].z) * bf2f(bb[k].z) + bf2f(a[k].w) * bf2f(bb[k].w);
        }
        for (int m = 16; m; m >>= 1) {
            #pragma unroll
            for (int k = 0; k < 4; ++k) d[k] += __shfl_xor(d[k], m, 32);
        }
        if (lane < 4) {
            int p = b + lane;
            if (p < cnt) {
                int e = s_list[p];
                int col = ei[E + e];   // L1/L2 hit
                float dv = (lane == 0) ? d[0] : (lane == 1) ? d[1]
                         : (lane == 2) ? d[2] : d[3];
                if (e_arr) e_arr[e] = dv;
                atomicAdd(&cd[col], (double)dv + PK);
            }
        }
    }
}

// ---- K3: masks -> x_new; na; packed per-node struct for factored prune ----
__global__ void node_prompt_kernel(const float* __restrict__ x,
                                   const double* __restrict__ cd,
                                   const float* __restrict__ ps,
                                   const float* __restrict__ pd,
                                   const float* __restrict__ po,
                                   const int* __restrict__ flags,
                                   const float* __restrict__ nx,
                                   const float* __restrict__ rs,
                                   const float* __restrict__ rd,
                                   const float* __restrict__ ro,
                                   float* __restrict__ xn,
                                   double* __restrict__ na,
                                   float* __restrict__ pack, int N) {
    int g = threadIdx.x >> 5;
    int lane = threadIdx.x & 31;
    int n = blockIdx.x * 8 + g;
    if (n >= N) return;
    double v = cd[n];
    double degd = floor(v * (1.0 / PK) + 0.5);
    float dg = (float)degd;
    float cc = (float)(v - degd * PK);
    float csim = (dg > 0.0f) ? (cc / fmaxf(dg, 1.0f)) : INFINITY;
    bool ms = (csim <= SIM_THR);
    bool md = (dg <= DEG_THR);
    bool mo = !(ms || md);
    int plen = (ms && flags[0]) + (md && flags[1]) + (mo && flags[2]);
    float invp = (plen > 0) ? (1.0f / (float)plen) : 0.0f;

    int off = lane * 4;
    const float4 xv = *(const float4*)(x + (size_t)n * D_DIM + off);
    const float4 s  = *(const float4*)(ps + off);
    const float4 dd = *(const float4*)(pd + off);
    const float4 o  = *(const float4*)(po + off);

    float4 f;
    f.x = (ms ? s.x : 0.0f) + (md ? dd.x : 0.0f) + (mo ? o.x : 0.0f);
    f.y = (ms ? s.y : 0.0f) + (md ? dd.y : 0.0f) + (mo ? o.y : 0.0f);
    f.z = (ms ? s.z : 0.0f) + (md ? dd.z : 0.0f) + (mo ? o.z : 0.0f);
    f.w = (ms ? s.w : 0.0f) + (md ? dd.w : 0.0f) + (mo ? o.w : 0.0f);

    float4 r;
    r.x = xv.x + f.x * invp;
    r.y = xv.y + f.y * invp;
    r.z = xv.z + f.z * invp;
    r.w = xv.w + f.w * invp;

    *(float4*)(xn + (size_t)n * D_DIM + off) = r;

    double sq = (double)r.x * r.x + (double)r.y * r.y + (double)r.z * r.z + (double)r.w * r.w;
    for (int m = 16; m; m >>= 1) sq += __shfl_xor(sq, m, 32);
    if (lane == 0) {
        double nrm = sqrt(sq);
        double nad = (nrm > EPS_CS) ? nrm : EPS_CS;
        na[n] = nad;
        if (pack) {
            float as = ms ? invp : 0.0f;
            float ad = md ? invp : 0.0f;
            float ao = mo ? invp : 0.0f;
            float4 w0 = make_float4(rs[n], rd[n], ro[n], nx[n]);
            float4 w1 = make_float4(as, ad, ao, (float)(1.0 / nad));
            *(float4*)(pack + (size_t)n * 8)     = w0;
            *(float4*)(pack + (size_t)n * 8 + 4) = w1;
        }
    }
}

// ---- K4: fused factored prune + in-block exact fixup (no global atomics) ----
__global__ void edge_prune_fused(const int* __restrict__ ei,
                                 const float* __restrict__ e_arr,
                                 const float* __restrict__ pack,
                                 const float* __restrict__ G,
                                 const float* __restrict__ xn,
                                 const double* __restrict__ na,
                                 float* __restrict__ keep, int E) {
    __shared__ int s_list[256];
    __shared__ int s_cnt;
    int tid = threadIdx.x;
    if (tid == 0) s_cnt = 0;
    __syncthreads();

    int e = blockIdx.x * 256 + tid;
    if (e < E) {
        int i = ei[e], j = ei[E + e];
        const float4 ri = *(const float4*)(pack + (size_t)i * 8);      // r_s,r_d,r_o,|x|
        const float4 ai = *(const float4*)(pack + (size_t)i * 8 + 4);  // as,ad,ao,inv_na
        const float4 rj = *(const float4*)(pack + (size_t)j * 8);
        const float4 aj = *(const float4*)(pack + (size_t)j * 8 + 4);
        float ev = e_arr[e];
        float dot = ev * ri.w * rj.w
                  + aj.x * ri.x + aj.y * ri.y + aj.z * ri.z
                  + ai.x * rj.x + ai.y * rj.y + ai.z * rj.z;
        dot += ai.x * (G[0] * aj.x + G[1] * aj.y + G[2] * aj.z)
             + ai.y * (G[3] * aj.x + G[4] * aj.y + G[5] * aj.z)
             + ai.z * (G[6] * aj.x + G[7] * aj.y + G[8] * aj.z);
        float cosv = dot * ai.w * aj.w;
        keep[e] = (cosv >= 0.1f) ? 1.0f : 0.0f;
        if (fabsf(cosv - 0.1f) < MARGIN) {
            int idx = atomicAdd(&s_cnt, 1);   // LDS atomic, block-local
            s_list[idx] = e;
        }
    }
    __syncthreads();

    int cnt = s_cnt;
    int lane = tid & 31;
    int grp = tid >> 5;  // 8 groups of 32 lanes
    for (int it = grp; it < cnt; it += 8) {
        int ee = s_list[it];
        int row = ei[ee], col = ei[E + ee];
        const float4 a = *(const float4*)(xn + (size_t)row * D_DIM + lane * 4);
        const float4 b = *(const float4*)(xn + (size_t)col * D_DIM + lane * 4);
        double d = (double)a.x * b.x + (double)a.y * b.y +
                   (double)a.z * b.z + (double)a.w * b.w;
        for (int m = 16; m; m >>= 1) d += __shfl_xor(d, m, 32);
        if (lane == 0) {
            double cs = d / (na[row] * na[col]);
            keep[ee] = (cs >= PT_THR) ? 1.0f : 0.0f;
        }
    }
}

// ---- fallback (R1-proven): full f32/f64 prune over all edges ----
__global__ void edge_prune_kernel(const float* __restrict__ xn,
                                  const int* __restrict__ ei,
                                  const double* __restrict__ na,
                                  float* __restrict__ keep, int E) {
    int lane = threadIdx.x & 31;
    int grp = blockIdx.x * 8 + (threadIdx.x >> 5);
    int e0 = grp * 2, e1 = e0 + 1;
    if (e0 >= E) return;
    bool has1 = (e1 < E);
    int row0 = ei[e0], col0 = ei[E + e0];
    int row1 = has1 ? ei[e1] : row0;
    int col1 = has1 ? ei[E + e1] : col0;

    const float4 a0 = *(const float4*)(xn + (size_t)row0 * D_DIM + lane * 4);
    const float4 b0 = *(const float4*)(xn + (size_t)col0 * D_DIM + lane * 4);
    const float4 a1 = *(const float4*)(xn + (size_t)row1 * D_DIM + lane * 4);
    const float4 b1 = *(const float4*)(xn + (size_t)col1 * D_DIM + lane * 4);

    double d0 = (double)a0.x * b0.x + (double)a0.y * b0.y +
                (double)a0.z * b0.z + (double)a0.w * b0.w;
    double d1 = (double)a1.x * b1.x + (double)a1.y * b1.y +
                (double)a1.z * b1.z + (double)a1.w * b1.w;
    for (int m = 16; m; m >>= 1) {
        d0 += __shfl_xor(d0, m, 32);
        d1 += __shfl_xor(d1, m, 32);
    }
    if (lane == 0) {
        double cs = d0 / (na[row0] * na[col0]);
        keep[e0] = (cs >= PT_THR) ? 1.0f : 0.0f;
    } else if (lane == 1 && has1) {
        double cs = d1 / (na[row1] * na[col1]);
        keep[e1] = (cs >= PT_THR) ? 1.0f : 0.0f;
    }
}

extern "C" void kernel_launch(void* const* d_in, const int* in_sizes, int n_in,
                              void* d_out, int out_size, void* d_ws, size_t ws_size,
                              hipStream_t stream) {
    const float* x  = (const float*)d_in[0];
    const int*   ei = (const int*)d_in[1];
    const float* ps = (const float*)d_in[2];
    const float* pd = (const float*)d_in[3];
    const float* po = (const float*)d_in[4];

    const int N = in_sizes[0] / D_DIM;    // 100000
    const int E = in_sizes[1] / 2;        // 640000

    float* xn    = (float*)d_out;                       // [N, D]
    float* keep  = (float*)d_out + (size_t)N * D_DIM;   // [E]
    u16*   xnorm = (u16*)d_out;                         // bf16 temp, consumed pre-K3

    char* ws = (char*)d_ws;
    const int nodeBlocks = (N + 7) / 8;
    const int simBlocks  = ((E + CHUNK - 1) / CHUNK) * NXCD;

    if (ws_size >= (size_t)WS_NEED) {
        double* cd    = (double*)(ws + 0);
        double* na    = (double*)(ws + 800000);
        float* nx     = (float*)(ws + 1600000);
        float* rs     = (float*)(ws + 2000000);
        float* rd     = (float*)(ws + 2400000);
        float* ro     = (float*)(ws + 2800000);
        float* e_arr  = (float*)(ws + 3200000);
        float* pack   = (float*)(ws + 5760000);
        int*   flags  = (int*)(ws + 8960000);
        float* G      = (float*)(ws + 8960016);

        node_pre_kernel<<<nodeBlocks, 256, 0, stream>>>(x, ps, pd, po, xnorm,
                                                        nx, rs, rd, ro, cd, flags, G, N);
        edge_sim_part<<<simBlocks, 256, 0, stream>>>(xnorm, ei, cd, e_arr, E, N);
        node_prompt_kernel<<<nodeBlocks, 256, 0, stream>>>(x, cd, ps, pd, po,
                                                           flags, nx, rs, rd, ro,
                                                           xn, na, pack, N);
        edge_prune_fused<<<(E + 255) / 256, 256, 0, stream>>>(ei, e_arr, pack, G, xn, na, keep, E);
    } else {
        // fallback: same pipeline minus factored prune
        double* cd    = (double*)(ws + 0);
        double* na    = (double*)(ws + 800000);
        int*   flags  = (int*)(ws + 1600000);
        float* G      = (float*)(ws + 1600016);
        float* scratch = (float*)(ws + 1600064);

        node_pre_kernel<<<nodeBlocks, 256, 0, stream>>>(x, ps, pd, po, xnorm,
                                                        scratch, scratch, scratch, scratch,
                                                        cd, flags, G, N);
        edge_sim_part<<<simBlocks, 256, 0, stream>>>(xnorm, ei, cd, nullptr, E, N);
        node_prompt_kernel<<<nodeBlocks, 256, 0, stream>>>(x, cd, ps, pd, po,
                                                           flags, nullptr, nullptr, nullptr, nullptr,
                                                           xn, na, nullptr, N);
        edge_prune_kernel<<<(E + 15) / 16, 256, 0, stream>>>(xn, ei, na, keep, E);
    }
}

// Round 7
// 101.218 us; speedup vs baseline: 1.1446x; 1.1446x over previous
//
#include <hip/hip_runtime.h>
#include <hip/hip_bf16.h>
#include <math.h>

#define D_DIM 128
#define SIM_THR 0.2f
#define DEG_THR 3.0f
#define PT_THR 0.1
#define EPS_CS 1e-8
#define MARGIN 4e-3f
#define PK 4294967296.0   // 2^32: deg-count scale inside packed f64 atomic

typedef unsigned short u16;

// ---------------- primary ws layout (bytes) ----------------
// 0        cd      double[N]   800000   (zeroed by node_pre)
// 800000   na      double[N]   800000
// 1600000  nx      f32[N]      400000   (|x| per node)
// 2000000  r_s     f32[N]      400000
// 2400000  r_d     f32[N]      400000
// 2800000  r_o     f32[N]      400000
// 3200000  e_arr   f32[E]      2560000
// 5760000  pack    f32[8N]     3200000  {r_s,r_d,r_o,|x|, as,ad,ao,inv_na}
// 8960000  flags   int[4]
// 8960016  G       f32[9]
#define WS_NEED 8960064

__device__ __forceinline__ float bf2f(u16 u) {
    return __uint_as_float(((unsigned)u) << 16);
}

// ---- K1: per node: xnorm bf16, |x|, r_k = dot(x,p_k); zero cd; block 0
//      wave 0 additionally computes prompt flags + 3x3 Gram ----
__global__ void node_pre_kernel(const float* __restrict__ x,
                                const float* __restrict__ ps,
                                const float* __restrict__ pd,
                                const float* __restrict__ po,
                                u16* __restrict__ xnorm,
                                float* __restrict__ nx,
                                float* __restrict__ rs,
                                float* __restrict__ rd,
                                float* __restrict__ ro,
                                double* __restrict__ cd,
                                int* __restrict__ flags,
                                float* __restrict__ G, int N) {
    int g = threadIdx.x >> 5;
    int lane = threadIdx.x & 31;
    int n = blockIdx.x * 8 + g;
    if (n < N) {
        int off = lane * 4;
        const float4 v = *(const float4*)(x + (size_t)n * D_DIM + off);
        const float4 s = *(const float4*)(ps + off);
        const float4 d = *(const float4*)(pd + off);
        const float4 o = *(const float4*)(po + off);
        float sq = v.x * v.x + v.y * v.y + v.z * v.z + v.w * v.w;
        float drs = v.x * s.x + v.y * s.y + v.z * s.z + v.w * s.w;
        float drd = v.x * d.x + v.y * d.y + v.z * d.z + v.w * d.w;
        float dro = v.x * o.x + v.y * o.y + v.z * o.z + v.w * o.w;
        for (int m = 16; m; m >>= 1) {
            sq += __shfl_xor(sq, m, 32);
            drs += __shfl_xor(drs, m, 32);
            drd += __shfl_xor(drd, m, 32);
            dro += __shfl_xor(dro, m, 32);
        }
        float nrm = sqrtf(sq);
        float inv = 1.0f / nrm;
        __hip_bfloat16 ob[4];
        ob[0] = __float2bfloat16(v.x * inv);
        ob[1] = __float2bfloat16(v.y * inv);
        ob[2] = __float2bfloat16(v.z * inv);
        ob[3] = __float2bfloat16(v.w * inv);
        *(ushort4*)(xnorm + (size_t)n * D_DIM + off) =
            make_ushort4(*(u16*)&ob[0], *(u16*)&ob[1], *(u16*)&ob[2], *(u16*)&ob[3]);
        if (lane == 0) {
            nx[n] = nrm;
            rs[n] = drs;
            rd[n] = drd;
            ro[n] = dro;
            cd[n] = 0.0;
        }
    }
    // prompt flags + Gram: one wave of block 0
    if (blockIdx.x == 0 && threadIdx.x < 64) {
        int t = threadIdx.x;
        float s0 = ps[t], s1 = ps[t + 64];
        float d0 = pd[t], d1 = pd[t + 64];
        float o0 = po[t], o1 = po[t + 64];
        float ss = s0 * s0 + s1 * s1;
        float sd = s0 * d0 + s1 * d1;
        float so = s0 * o0 + s1 * o1;
        float dd = d0 * d0 + d1 * d1;
        float dO = d0 * o0 + d1 * o1;
        float oo = o0 * o0 + o1 * o1;
        for (int m = 32; m; m >>= 1) {
            ss += __shfl_xor(ss, m);
            sd += __shfl_xor(sd, m);
            so += __shfl_xor(so, m);
            dd += __shfl_xor(dd, m);
            dO += __shfl_xor(dO, m);
            oo += __shfl_xor(oo, m);
        }
        unsigned long long zs = __ballot(s0 == 0.0f || s1 == 0.0f);
        unsigned long long zd = __ballot(d0 == 0.0f || d1 == 0.0f);
        unsigned long long zo = __ballot(o0 == 0.0f || o1 == 0.0f);
        if (t == 0) {
            flags[0] = (zs == 0ull);
            flags[1] = (zd == 0ull);
            flags[2] = (zo == 0ull);
            G[0] = ss; G[1] = sd; G[2] = so;
            G[3] = sd; G[4] = dd; G[5] = dO;
            G[6] = so; G[7] = dO; G[8] = oo;
        }
    }
}

// ---- K2: linear edge sim, 8 edges per 32-lane group (16 row-loads in
//      flight per lane); one packed f64 atomic per edge ----
__global__ void edge_sim_kernel(const u16* __restrict__ xnorm,
                                const int* __restrict__ ei,
                                double* __restrict__ cd,
                                float* __restrict__ e_arr,
                                int E) {
    int lane = threadIdx.x & 31;
    int grp = blockIdx.x * 8 + (threadIdx.x >> 5);
    int base = grp * 8;
    if (base >= E) return;

    int r[8], c8[8];
    #pragma unroll
    for (int k = 0; k < 8; ++k) {
        int e = base + k;
        int src = (e < E) ? e : base;
        r[k] = ei[src];
        c8[k] = ei[E + src];
    }

    ushort4 a[8], b[8];
    #pragma unroll
    for (int k = 0; k < 8; ++k) {
        a[k] = *(const ushort4*)(xnorm + (size_t)r[k] * D_DIM + lane * 4);
        b[k] = *(const ushort4*)(xnorm + (size_t)c8[k] * D_DIM + lane * 4);
    }

    float d[8];
    #pragma unroll
    for (int k = 0; k < 8; ++k) {
        d[k] = bf2f(a[k].x) * bf2f(b[k].x) + bf2f(a[k].y) * bf2f(b[k].y) +
               bf2f(a[k].z) * bf2f(b[k].z) + bf2f(a[k].w) * bf2f(b[k].w);
    }
    for (int m = 16; m; m >>= 1) {
        #pragma unroll
        for (int k = 0; k < 8; ++k) d[k] += __shfl_xor(d[k], m, 32);
    }

    if (lane < 8) {
        int e = base + lane;
        if (e < E) {
            float dv = (lane == 0) ? d[0] : (lane == 1) ? d[1]
                     : (lane == 2) ? d[2] : (lane == 3) ? d[3]
                     : (lane == 4) ? d[4] : (lane == 5) ? d[5]
                     : (lane == 6) ? d[6] : d[7];
            int cc = (lane == 0) ? c8[0] : (lane == 1) ? c8[1]
                   : (lane == 2) ? c8[2] : (lane == 3) ? c8[3]
                   : (lane == 4) ? c8[4] : (lane == 5) ? c8[5]
                   : (lane == 6) ? c8[6] : c8[7];
            if (e_arr) e_arr[e] = dv;
            atomicAdd(&cd[cc], (double)dv + PK);
        }
    }
}

// ---- K3: masks -> x_new; na; packed per-node struct for factored prune ----
__global__ void node_prompt_kernel(const float* __restrict__ x,
                                   const double* __restrict__ cd,
                                   const float* __restrict__ ps,
                                   const float* __restrict__ pd,
                                   const float* __restrict__ po,
                                   const int* __restrict__ flags,
                                   const float* __restrict__ nx,
                                   const float* __restrict__ rs,
                                   const float* __restrict__ rd,
                                   const float* __restrict__ ro,
                                   float* __restrict__ xn,
                                   double* __restrict__ na,
                                   float* __restrict__ pack, int N) {
    int g = threadIdx.x >> 5;
    int lane = threadIdx.x & 31;
    int n = blockIdx.x * 8 + g;
    if (n >= N) return;
    double v = cd[n];
    double degd = floor(v * (1.0 / PK) + 0.5);
    float dg = (float)degd;
    float cc = (float)(v - degd * PK);
    float csim = (dg > 0.0f) ? (cc / fmaxf(dg, 1.0f)) : INFINITY;
    bool ms = (csim <= SIM_THR);
    bool md = (dg <= DEG_THR);
    bool mo = !(ms || md);
    int plen = (ms && flags[0]) + (md && flags[1]) + (mo && flags[2]);
    float invp = (plen > 0) ? (1.0f / (float)plen) : 0.0f;

    int off = lane * 4;
    const float4 xv = *(const float4*)(x + (size_t)n * D_DIM + off);
    const float4 s  = *(const float4*)(ps + off);
    const float4 dd = *(const float4*)(pd + off);
    const float4 o  = *(const float4*)(po + off);

    float4 f;
    f.x = (ms ? s.x : 0.0f) + (md ? dd.x : 0.0f) + (mo ? o.x : 0.0f);
    f.y = (ms ? s.y : 0.0f) + (md ? dd.y : 0.0f) + (mo ? o.y : 0.0f);
    f.z = (ms ? s.z : 0.0f) + (md ? dd.z : 0.0f) + (mo ? o.z : 0.0f);
    f.w = (ms ? s.w : 0.0f) + (md ? dd.w : 0.0f) + (mo ? o.w : 0.0f);

    float4 r;
    r.x = xv.x + f.x * invp;
    r.y = xv.y + f.y * invp;
    r.z = xv.z + f.z * invp;
    r.w = xv.w + f.w * invp;

    *(float4*)(xn + (size_t)n * D_DIM + off) = r;

    double sq = (double)r.x * r.x + (double)r.y * r.y + (double)r.z * r.z + (double)r.w * r.w;
    for (int m = 16; m; m >>= 1) sq += __shfl_xor(sq, m, 32);
    if (lane == 0) {
        double nrm = sqrt(sq);
        double nad = (nrm > EPS_CS) ? nrm : EPS_CS;
        na[n] = nad;
        if (pack) {
            float as = ms ? invp : 0.0f;
            float ad = md ? invp : 0.0f;
            float ao = mo ? invp : 0.0f;
            float4 w0 = make_float4(rs[n], rd[n], ro[n], nx[n]);
            float4 w1 = make_float4(as, ad, ao, (float)(1.0 / nad));
            *(float4*)(pack + (size_t)n * 8)     = w0;
            *(float4*)(pack + (size_t)n * 8 + 4) = w1;
        }
    }
}

// ---- K4: fused factored prune + in-block exact fixup (no global atomics) ----
__global__ void edge_prune_fused(const int* __restrict__ ei,
                                 const float* __restrict__ e_arr,
                                 const float* __restrict__ pack,
                                 const float* __restrict__ G,
                                 const float* __restrict__ xn,
                                 const double* __restrict__ na,
                                 float* __restrict__ keep, int E) {
    __shared__ int s_list[256];
    __shared__ int s_cnt;
    int tid = threadIdx.x;
    if (tid == 0) s_cnt = 0;
    __syncthreads();

    int e = blockIdx.x * 256 + tid;
    if (e < E) {
        int i = ei[e], j = ei[E + e];
        const float4 ri = *(const float4*)(pack + (size_t)i * 8);      // r_s,r_d,r_o,|x|
        const float4 ai = *(const float4*)(pack + (size_t)i * 8 + 4);  // as,ad,ao,inv_na
        const float4 rj = *(const float4*)(pack + (size_t)j * 8);
        const float4 aj = *(const float4*)(pack + (size_t)j * 8 + 4);
        float ev = e_arr[e];
        float dot = ev * ri.w * rj.w
                  + aj.x * ri.x + aj.y * ri.y + aj.z * ri.z
                  + ai.x * rj.x + ai.y * rj.y + ai.z * rj.z;
        dot += ai.x * (G[0] * aj.x + G[1] * aj.y + G[2] * aj.z)
             + ai.y * (G[3] * aj.x + G[4] * aj.y + G[5] * aj.z)
             + ai.z * (G[6] * aj.x + G[7] * aj.y + G[8] * aj.z);
        float cosv = dot * ai.w * aj.w;
        keep[e] = (cosv >= 0.1f) ? 1.0f : 0.0f;
        if (fabsf(cosv - 0.1f) < MARGIN) {
            int idx = atomicAdd(&s_cnt, 1);   // LDS atomic, block-local
            s_list[idx] = e;
        }
    }
    __syncthreads();

    int cnt = s_cnt;
    int lane = tid & 31;
    int grp = tid >> 5;  // 8 groups of 32 lanes
    for (int it = grp; it < cnt; it += 8) {
        int ee = s_list[it];
        int row = ei[ee], col = ei[E + ee];
        const float4 a = *(const float4*)(xn + (size_t)row * D_DIM + lane * 4);
        const float4 b = *(const float4*)(xn + (size_t)col * D_DIM + lane * 4);
        double d = (double)a.x * b.x + (double)a.y * b.y +
                   (double)a.z * b.z + (double)a.w * b.w;
        for (int m = 16; m; m >>= 1) d += __shfl_xor(d, m, 32);
        if (lane == 0) {
            double cs = d / (na[row] * na[col]);
            keep[ee] = (cs >= PT_THR) ? 1.0f : 0.0f;
        }
    }
}

// ---- fallback (R1-proven): full f32/f64 prune over all edges ----
__global__ void edge_prune_kernel(const float* __restrict__ xn,
                                  const int* __restrict__ ei,
                                  const double* __restrict__ na,
                                  float* __restrict__ keep, int E) {
    int lane = threadIdx.x & 31;
    int grp = blockIdx.x * 8 + (threadIdx.x >> 5);
    int e0 = grp * 2, e1 = e0 + 1;
    if (e0 >= E) return;
    bool has1 = (e1 < E);
    int row0 = ei[e0], col0 = ei[E + e0];
    int row1 = has1 ? ei[e1] : row0;
    int col1 = has1 ? ei[E + e1] : col0;

    const float4 a0 = *(const float4*)(xn + (size_t)row0 * D_DIM + lane * 4);
    const float4 b0 = *(const float4*)(xn + (size_t)col0 * D_DIM + lane * 4);
    const float4 a1 = *(const float4*)(xn + (size_t)row1 * D_DIM + lane * 4);
    const float4 b1 = *(const float4*)(xn + (size_t)col1 * D_DIM + lane * 4);

    double d0 = (double)a0.x * b0.x + (double)a0.y * b0.y +
                (double)a0.z * b0.z + (double)a0.w * b0.w;
    double d1 = (double)a1.x * b1.x + (double)a1.y * b1.y +
                (double)a1.z * b1.z + (double)a1.w * b1.w;
    for (int m = 16; m; m >>= 1) {
        d0 += __shfl_xor(d0, m, 32);
        d1 += __shfl_xor(d1, m, 32);
    }
    if (lane == 0) {
        double cs = d0 / (na[row0] * na[col0]);
        keep[e0] = (cs >= PT_THR) ? 1.0f : 0.0f;
    } else if (lane == 1 && has1) {
        double cs = d1 / (na[row1] * na[col1]);
        keep[e1] = (cs >= PT_THR) ? 1.0f : 0.0f;
    }
}

extern "C" void kernel_launch(void* const* d_in, const int* in_sizes, int n_in,
                              void* d_out, int out_size, void* d_ws, size_t ws_size,
                              hipStream_t stream) {
    const float* x  = (const float*)d_in[0];
    const int*   ei = (const int*)d_in[1];
    const float* ps = (const float*)d_in[2];
    const float* pd = (const float*)d_in[3];
    const float* po = (const float*)d_in[4];

    const int N = in_sizes[0] / D_DIM;    // 100000
    const int E = in_sizes[1] / 2;        // 640000

    float* xn    = (float*)d_out;                       // [N, D]
    float* keep  = (float*)d_out + (size_t)N * D_DIM;   // [E]
    u16*   xnorm = (u16*)d_out;                         // bf16 temp, consumed pre-K3

    char* ws = (char*)d_ws;
    const int nodeBlocks = (N + 7) / 8;
    const int simBlocks  = (E + 63) / 64;   // 8 groups x 8 edges per block

    if (ws_size >= (size_t)WS_NEED) {
        double* cd    = (double*)(ws + 0);
        double* na    = (double*)(ws + 800000);
        float* nx     = (float*)(ws + 1600000);
        float* rs     = (float*)(ws + 2000000);
        float* rd     = (float*)(ws + 2400000);
        float* ro     = (float*)(ws + 2800000);
        float* e_arr  = (float*)(ws + 3200000);
        float* pack   = (float*)(ws + 5760000);
        int*   flags  = (int*)(ws + 8960000);
        float* G      = (float*)(ws + 8960016);

        node_pre_kernel<<<nodeBlocks, 256, 0, stream>>>(x, ps, pd, po, xnorm,
                                                        nx, rs, rd, ro, cd, flags, G, N);
        edge_sim_kernel<<<simBlocks, 256, 0, stream>>>(xnorm, ei, cd, e_arr, E);
        node_prompt_kernel<<<nodeBlocks, 256, 0, stream>>>(x, cd, ps, pd, po,
                                                           flags, nx, rs, rd, ro,
                                                           xn, na, pack, N);
        edge_prune_fused<<<(E + 255) / 256, 256, 0, stream>>>(ei, e_arr, pack, G, xn, na, keep, E);
    } else {
        // fallback: same pipeline minus factored prune
        double* cd    = (double*)(ws + 0);
        double* na    = (double*)(ws + 800000);
        int*   flags  = (int*)(ws + 1600000);
        float* G      = (float*)(ws + 1600016);
        float* scratch = (float*)(ws + 1600064);

        node_pre_kernel<<<nodeBlocks, 256, 0, stream>>>(x, ps, pd, po, xnorm,
                                                        scratch, scratch, scratch, scratch,
                                                        cd, flags, G, N);
        edge_sim_kernel<<<simBlocks, 256, 0, stream>>>(xnorm, ei, cd, nullptr, E);
        node_prompt_kernel<<<nodeBlocks, 256, 0, stream>>>(x, cd, ps, pd, po,
                                                           flags, nullptr, nullptr, nullptr, nullptr,
                                                           xn, na, nullptr, N);
        edge_prune_kernel<<<(E + 15) / 16, 256, 0, stream>>>(xn, ei, na, keep, E);
    }
}